// Round 4
// baseline (138.782 us; speedup 1.0000x reference)
//
#include <hip/hip_runtime.h>
#include <hip/hip_bf16.h>
#include <stdint.h>
#include <stddef.h>

// ---------- types ----------
typedef __attribute__((ext_vector_type(8))) short bfrag8;   // 8 bf16 in 4 VGPRs
typedef __attribute__((ext_vector_type(4))) float facc4;    // MFMA accumulator

#define SCALING 0.17677669529663687f   // 32^-0.5

__device__ __forceinline__ unsigned short f2bf(float f) {
  union { float f; unsigned u; } v; v.f = f;
  unsigned r = v.u + 0x7fffu + ((v.u >> 16) & 1u);   // RNE
  return (unsigned short)(r >> 16);
}

// ---------------------------------------------------------------------------
// Kernel 1: fp32 -> bf16 convert for query, W_in, W_out
// ---------------------------------------------------------------------------
__global__ __launch_bounds__(256)
void convert_bf16(const float* __restrict__ q, const float* __restrict__ wi,
                  const float* __restrict__ wo,
                  unsigned short* __restrict__ qb, unsigned short* __restrict__ wib,
                  unsigned short* __restrict__ wob) {
  int t = blockIdx.x * 256 + threadIdx.x;
  const float4* src; unsigned short* dst; int idx;
  if (t < 524288)            { src = (const float4*)q;  dst = qb;  idx = t; }
  else if (t < 524288+196608){ src = (const float4*)wi; dst = wib; idx = t - 524288; }
  else                       { src = (const float4*)wo; dst = wob; idx = t - 720896; }
  float4 v = src[idx];
  ushort4 o;
  o.x = f2bf(v.x); o.y = f2bf(v.y); o.z = f2bf(v.z); o.w = f2bf(v.w);
  *(ushort4*)(dst + (size_t)idx * 4) = o;
}

// ---------------------------------------------------------------------------
// Kernel 2/4: GEMM  C[M x N] = A[M x 512] * B[N x 512]^T  (both K-contiguous)
// BM=64, BN=128, BK=32, 256 threads (4 waves in 2x2), wave tile 32x64.
// MODE 0: qkv epilogue (+b_in, scale q, scatter Q,K to [gh][n][d] and V
//         DIRECTLY TRANSPOSED to Vt [gh][d][n] — stores are scalar 2B
//         scatters either way, so the transpose kernel is deleted for free)
// MODE 1: out epilogue (+b_out, fp32 store to d_out)
// ---------------------------------------------------------------------------
template<int MODE>
__global__ __launch_bounds__(256, 2)
void gemm_bt(const unsigned short* __restrict__ A, const unsigned short* __restrict__ Bw,
             const float* __restrict__ bias,
             unsigned short* __restrict__ oQ, unsigned short* __restrict__ oK,
             unsigned short* __restrict__ oV, float* __restrict__ oF) {
  constexpr int K = 512;
  __shared__ __align__(16) unsigned short lA[2][64 * 32];
  __shared__ __align__(16) unsigned short lB[2][128 * 32];
  const int t = threadIdx.x;
  const int w = t >> 6, l = t & 63;
  const int lr = l & 15, lg = l >> 4;
  const int mBase = blockIdx.x * 64;
  const int nBase = blockIdx.y * 128;
  const int wr = w >> 1, wc = w & 1;

  facc4 acc[2][4];
#pragma unroll
  for (int i = 0; i < 2; i++)
#pragma unroll
    for (int j = 0; j < 4; j++) acc[i][j] = (facc4){0.f, 0.f, 0.f, 0.f};

  const int arow = t & 63, aslot = t >> 6;
  const unsigned short* aSrc = A + (size_t)(mBase + arow) * K + aslot * 8;
  const int bcol0 = t & 127, bslot0 = t >> 7;
  const int bcol1 = (256 + t) & 127, bslot1 = (256 + t) >> 7;
  const unsigned short* bSrc0 = Bw + (size_t)(nBase + bcol0) * K + bslot0 * 8;
  const unsigned short* bSrc1 = Bw + (size_t)(nBase + bcol1) * K + bslot1 * 8;

  auto stage = [&](int ks, int buf) {
    const int kB = ks * 32;
    *(int4*)(&lA[buf][(size_t)t * 8])         = *(const int4*)(aSrc + kB);
    *(int4*)(&lB[buf][(size_t)t * 8])         = *(const int4*)(bSrc0 + kB);
    *(int4*)(&lB[buf][(size_t)(256 + t) * 8]) = *(const int4*)(bSrc1 + kB);
  };

  stage(0, 0);
  __syncthreads();
#pragma unroll 1
  for (int ks = 0; ks < 16; ks++) {
    const int buf = ks & 1;
    if (ks < 15) stage(ks + 1, buf ^ 1);
    bfrag8 af[2], bfr[4];
#pragma unroll
    for (int qi = 0; qi < 2; qi++)
      af[qi] = *(const bfrag8*)(&lA[buf][(lg * 64 + wr * 32 + qi * 16 + lr) * 8]);
#pragma unroll
    for (int nj = 0; nj < 4; nj++)
      bfr[nj] = *(const bfrag8*)(&lB[buf][(lg * 128 + wc * 64 + nj * 16 + lr) * 8]);
#pragma unroll
    for (int qi = 0; qi < 2; qi++)
#pragma unroll
      for (int nj = 0; nj < 4; nj++)
        acc[qi][nj] = __builtin_amdgcn_mfma_f32_16x16x32_bf16(af[qi], bfr[nj], acc[qi][nj], 0, 0, 0);
    __syncthreads();
  }

#pragma unroll
  for (int qi = 0; qi < 2; qi++)
#pragma unroll
    for (int nj = 0; nj < 4; nj++) {
      int m0 = mBase + wr * 32 + qi * 16 + lg * 4;
      int o = nBase + wc * 64 + nj * 16 + lr;
      float bv = bias[o];
#pragma unroll
      for (int r = 0; r < 4; r++) {
        float v = acc[qi][nj][r] + bv;
        int mm = m0 + r;
        if (MODE == 0) {
          int n = mm >> 2, g = mm & 3;
          int chunk = o >> 9, cc = o & 511, h = cc >> 5, d = cc & 31;
          if (chunk == 0)
            oQ[((size_t)(g * 16 + h) * 1024 + n) * 32 + d] = f2bf(v * SCALING);
          else if (chunk == 1)
            oK[((size_t)(g * 16 + h) * 1024 + n) * 32 + d] = f2bf(v);
          else
            oV[((size_t)(g * 16 + h) * 32 + d) * 1024 + n] = f2bf(v);   // Vt layout
        } else {
          oF[(size_t)mm * 512 + o] = v;
        }
      }
    }
}

// ---------------------------------------------------------------------------
// Kernel 3: fused flash attention, SPLIT-K over the key dimension.
// grid (64 gh, 16 q-tiles, 2 K-halves) = 2048 blocks = 8 blocks/CU ->
// 32 waves/CU, double the latency hiding of round 3 (which was capped at
// 4 blocks/CU by the grid and measured ~101 us vs the 42 us bias floor).
// Register structure identical to round 3 (~60 VGPR, no spills, matches the
// allocator's 8-wave/EU budget). Each block does 8 K-tiles of 64 and writes
// unnormalized O (fp32) + (m,l); combine_kernel merges the two halves.
// Same-gh blocks stay on one XCD (linear id = x mod 8) -> K/V L2-local.
// ---------------------------------------------------------------------------
__global__ __launch_bounds__(256)
void attn_kernel(const unsigned short* __restrict__ Qs, const unsigned short* __restrict__ Ks,
                 const unsigned short* __restrict__ Vt, const float* __restrict__ biasG,
                 float* __restrict__ Op, float* __restrict__ Ml) {
  __shared__ __align__(16) unsigned short Pl[4][16 * 64];   // 8 KB, per-wave P tile
  const int gh = blockIdx.x, q0 = blockIdx.y * 64, z = blockIdx.z;
  const int t = threadIdx.x, w = t >> 6, l = t & 63;
  const int lr = l & 15, lg = l >> 4;

  const unsigned short* Qg = Qs + (size_t)gh * 1024 * 32;
  const unsigned short* Kg = Ks + (size_t)gh * 1024 * 32;
  const unsigned short* Vg = Vt + (size_t)gh * 32 * 1024;
  const float* Bt = biasG + (size_t)gh * 1048576 + (size_t)(q0 + w * 16 + lg * 4) * 1024 + lr;

  bfrag8 qf = *(const bfrag8*)(Qg + (size_t)(q0 + w * 16 + lr) * 32 + lg * 8);

  facc4 accO[2];
  accO[0] = (facc4){0.f, 0.f, 0.f, 0.f};
  accO[1] = (facc4){0.f, 0.f, 0.f, 0.f};
  float mrun[4], lrun[4];
#pragma unroll
  for (int r = 0; r < 4; r++) { mrun[r] = -3.0e38f; lrun[r] = 0.f; }

  unsigned short* Pw = Pl[w];

#pragma unroll 1
  for (int kt = z * 8; kt < z * 8 + 8; kt++) {
    const int kb = kt * 64;
    // bias -> MFMA C operand (16 scalar dword loads, exact C/D lane layout)
    facc4 sc[4];
#pragma unroll
    for (int j = 0; j < 4; j++)
#pragma unroll
      for (int r = 0; r < 4; r++)
        sc[j][r] = Bt[(size_t)r * 1024 + kb + j * 16];
    // QK^T accumulating onto the bias
#pragma unroll
    for (int j = 0; j < 4; j++) {
      bfrag8 kf = *(const bfrag8*)(Kg + (size_t)(kb + j * 16 + lr) * 32 + lg * 8);
      sc[j] = __builtin_amdgcn_mfma_f32_16x16x32_bf16(qf, kf, sc[j], 0, 0, 0);
    }
    // row max over this tile (16-lane column groups)
    float tm[4];
#pragma unroll
    for (int r = 0; r < 4; r++) tm[r] = -3.0e38f;
#pragma unroll
    for (int j = 0; j < 4; j++)
#pragma unroll
      for (int r = 0; r < 4; r++) tm[r] = fmaxf(tm[r], sc[j][r]);
#pragma unroll
    for (int mk = 1; mk < 16; mk <<= 1)
#pragma unroll
      for (int r = 0; r < 4; r++) tm[r] = fmaxf(tm[r], __shfl_xor(tm[r], mk, 64));
    // online softmax update
    float scale[4];
#pragma unroll
    for (int r = 0; r < 4; r++) {
      float mn = fmaxf(mrun[r], tm[r]);
      scale[r] = __expf(mrun[r] - mn);
      mrun[r] = mn;
    }
    float rs[4] = {0.f, 0.f, 0.f, 0.f};
#pragma unroll
    for (int j = 0; j < 4; j++)
#pragma unroll
      for (int r = 0; r < 4; r++) {
        float p = __expf(sc[j][r] - mrun[r]);
        rs[r] += p;
        int row = lg * 4 + r, col = j * 16 + lr;
        int byte = (row * 128 + col * 2) ^ ((row & 7) << 4);
        *(unsigned short*)((char*)Pw + byte) = f2bf(p);
      }
#pragma unroll
    for (int mk = 1; mk < 16; mk <<= 1)
#pragma unroll
      for (int r = 0; r < 4; r++) rs[r] += __shfl_xor(rs[r], mk, 64);
#pragma unroll
    for (int r = 0; r < 4; r++) lrun[r] = lrun[r] * scale[r] + rs[r];
#pragma unroll
    for (int h = 0; h < 2; h++)
#pragma unroll
      for (int r = 0; r < 4; r++) accO[h][r] *= scale[r];
    // PV (P A-frags from own-wave LDS; V B-frags 16B-contiguous from Vt)
#pragma unroll
    for (int ksb = 0; ksb < 2; ksb++) {
      int byte = (lr * 128 + (ksb * 32 + lg * 8) * 2) ^ ((lr & 7) << 4);
      bfrag8 pf = *(const bfrag8*)((char*)Pw + byte);
#pragma unroll
      for (int h = 0; h < 2; h++) {
        bfrag8 vf = *(const bfrag8*)(Vg + (size_t)(h * 16 + lr) * 1024 + kb + ksb * 32 + lg * 8);
        accO[h] = __builtin_amdgcn_mfma_f32_16x16x32_bf16(pf, vf, accO[h], 0, 0, 0);
      }
    }
  }

  // epilogue: unnormalized partial O (fp32) + (m,l) per row
  const size_t pb = (size_t)(z * 64 + gh) * 1024;
#pragma unroll
  for (int h = 0; h < 2; h++)
#pragma unroll
    for (int r = 0; r < 4; r++) {
      int q = q0 + w * 16 + lg * 4 + r;
      Op[(pb + q) * 32 + h * 16 + lr] = accO[h][r];
    }
  if (lr == 0) {
#pragma unroll
    for (int r = 0; r < 4; r++) {
      int q = q0 + w * 16 + lg * 4 + r;
      Ml[(pb + q) * 2]     = mrun[r];
      Ml[(pb + q) * 2 + 1] = lrun[r];
    }
  }
}

// ---------------------------------------------------------------------------
// Kernel 3b: combine the two K-halves.
// 2M outputs; thread -> (gh, n, d). Reads 2 fp32 partials + 2 (m,l) pairs,
// writes bf16 attn_out [n*4+g][hh*32+d]. Fully coalesced in d.
// ---------------------------------------------------------------------------
__global__ __launch_bounds__(256)
void combine_kernel(const float* __restrict__ Op, const float* __restrict__ Ml,
                    unsigned short* __restrict__ Out) {
  int idx = blockIdx.x * 256 + threadIdx.x;
  int d = idx & 31;
  int n = (idx >> 5) & 1023;
  int gh = idx >> 15;
  size_t p0 = (size_t)gh * 1024 + n;
  size_t p1 = (size_t)(64 + gh) * 1024 + n;
  float m0 = Ml[p0 * 2], l0 = Ml[p0 * 2 + 1];
  float m1 = Ml[p1 * 2], l1 = Ml[p1 * 2 + 1];
  float m = fmaxf(m0, m1);
  float a0 = __expf(m0 - m), a1 = __expf(m1 - m);
  float linv = 1.0f / (l0 * a0 + l1 * a1);
  float o = (Op[p0 * 32 + d] * a0 + Op[p1 * 32 + d] * a1) * linv;
  int g = gh >> 4, hh = gh & 15;
  Out[((size_t)(n * 4 + g)) * 512 + hh * 32 + d] = f2bf(o);
}

// ---------------------------------------------------------------------------
extern "C" void kernel_launch(void* const* d_in, const int* in_sizes, int n_in,
                              void* d_out, int out_size, void* d_ws, size_t ws_size,
                              hipStream_t stream) {
  (void)in_sizes; (void)n_in; (void)out_size; (void)ws_size;
  const float* query = (const float*)d_in[0];
  const float* abias = (const float*)d_in[1];
  const float* W_in  = (const float*)d_in[2];
  const float* b_in  = (const float*)d_in[3];
  const float* W_out = (const float*)d_in[4];
  const float* b_out = (const float*)d_in[5];
  float* out = (float*)d_out;
  char* ws = (char*)d_ws;
  unsigned short* qbf  = (unsigned short*)(ws);             // 4 MB
  unsigned short* wibf = (unsigned short*)(ws + 4194304);   // 1.5 MB
  unsigned short* wobf = (unsigned short*)(ws + 5767168);   // 0.5 MB
  unsigned short* Qs   = (unsigned short*)(ws + 6291456);   // 4 MB  [gh][n][d]
  unsigned short* Ks   = (unsigned short*)(ws + 10485760);  // 4 MB  [gh][n][d]
  unsigned short* Vt   = (unsigned short*)(ws + 14680064);  // 4 MB  [gh][d][n]
  unsigned short* attO = (unsigned short*)(ws + 18874368);  // 4 MB  [m][e]
  float*          Op   = (float*)(ws + 23068672);           // 16 MB [z][gh][n][32]
  float*          Ml   = (float*)(ws + 39845888);           // 1 MB  [z][gh][n][2]

  convert_bf16<<<3072, 256, 0, stream>>>(query, W_in, W_out, qbf, wibf, wobf);
  gemm_bt<0><<<dim3(64, 12), 256, 0, stream>>>(qbf, wibf, b_in, Qs, Ks, Vt, nullptr);
  attn_kernel<<<dim3(64, 16, 2), 256, 0, stream>>>(Qs, Ks, Vt, abias, Op, Ml);
  combine_kernel<<<8192, 256, 0, stream>>>(Op, Ml, attO);
  gemm_bt<1><<<dim3(64, 4), 256, 0, stream>>>(attO, wobf, b_out, nullptr, nullptr, nullptr, out);
}

// Round 5
// 128.799 us; speedup vs baseline: 1.0775x; 1.0775x over previous
//
#include <hip/hip_runtime.h>
#include <hip/hip_bf16.h>
#include <stdint.h>
#include <stddef.h>

// ---------- types ----------
typedef __attribute__((ext_vector_type(8))) short bfrag8;   // 8 bf16 in 4 VGPRs
typedef __attribute__((ext_vector_type(4))) float facc4;    // MFMA accumulator

#define SCALING 0.17677669529663687f   // 32^-0.5

__device__ __forceinline__ unsigned short f2bf(float f) {
  union { float f; unsigned u; } v; v.f = f;
  unsigned r = v.u + 0x7fffu + ((v.u >> 16) & 1u);   // RNE
  return (unsigned short)(r >> 16);
}

// ---------------------------------------------------------------------------
// Kernel 1: fp32 -> bf16 convert for query, W_in, W_out
// ---------------------------------------------------------------------------
__global__ __launch_bounds__(256)
void convert_bf16(const float* __restrict__ q, const float* __restrict__ wi,
                  const float* __restrict__ wo,
                  unsigned short* __restrict__ qb, unsigned short* __restrict__ wib,
                  unsigned short* __restrict__ wob) {
  int t = blockIdx.x * 256 + threadIdx.x;
  const float4* src; unsigned short* dst; int idx;
  if (t < 524288)            { src = (const float4*)q;  dst = qb;  idx = t; }
  else if (t < 524288+196608){ src = (const float4*)wi; dst = wib; idx = t - 524288; }
  else                       { src = (const float4*)wo; dst = wob; idx = t - 720896; }
  float4 v = src[idx];
  ushort4 o;
  o.x = f2bf(v.x); o.y = f2bf(v.y); o.z = f2bf(v.z); o.w = f2bf(v.w);
  *(ushort4*)(dst + (size_t)idx * 4) = o;
}

// ---------------------------------------------------------------------------
// Kernel 2/5: GEMM  C[M x N] = A[M x 512] * B[N x 512]^T  (round-3 version —
// Vt-direct scatter store reverted: it was a 2B x 2KB-stride lane scatter,
// 16 cache lines per store instr; the LDS transpose kernel is cheaper)
// MODE 0: qkv epilogue (+b_in, scale q, scatter to Qs/Ks/V [gh][n][d])
// MODE 1: out epilogue (+b_out, fp32 store to d_out)
// ---------------------------------------------------------------------------
template<int MODE>
__global__ __launch_bounds__(256, 2)
void gemm_bt(const unsigned short* __restrict__ A, const unsigned short* __restrict__ Bw,
             const float* __restrict__ bias,
             unsigned short* __restrict__ oQ, unsigned short* __restrict__ oK,
             unsigned short* __restrict__ oV, float* __restrict__ oF) {
  constexpr int K = 512;
  __shared__ __align__(16) unsigned short lA[2][64 * 32];
  __shared__ __align__(16) unsigned short lB[2][128 * 32];
  const int t = threadIdx.x;
  const int w = t >> 6, l = t & 63;
  const int lr = l & 15, lg = l >> 4;
  const int mBase = blockIdx.x * 64;
  const int nBase = blockIdx.y * 128;
  const int wr = w >> 1, wc = w & 1;

  facc4 acc[2][4];
#pragma unroll
  for (int i = 0; i < 2; i++)
#pragma unroll
    for (int j = 0; j < 4; j++) acc[i][j] = (facc4){0.f, 0.f, 0.f, 0.f};

  const int arow = t & 63, aslot = t >> 6;
  const unsigned short* aSrc = A + (size_t)(mBase + arow) * K + aslot * 8;
  const int bcol0 = t & 127, bslot0 = t >> 7;
  const int bcol1 = (256 + t) & 127, bslot1 = (256 + t) >> 7;
  const unsigned short* bSrc0 = Bw + (size_t)(nBase + bcol0) * K + bslot0 * 8;
  const unsigned short* bSrc1 = Bw + (size_t)(nBase + bcol1) * K + bslot1 * 8;

  auto stage = [&](int ks, int buf) {
    const int kB = ks * 32;
    *(int4*)(&lA[buf][(size_t)t * 8])         = *(const int4*)(aSrc + kB);
    *(int4*)(&lB[buf][(size_t)t * 8])         = *(const int4*)(bSrc0 + kB);
    *(int4*)(&lB[buf][(size_t)(256 + t) * 8]) = *(const int4*)(bSrc1 + kB);
  };

  stage(0, 0);
  __syncthreads();
#pragma unroll 1
  for (int ks = 0; ks < 16; ks++) {
    const int buf = ks & 1;
    if (ks < 15) stage(ks + 1, buf ^ 1);
    bfrag8 af[2], bfr[4];
#pragma unroll
    for (int qi = 0; qi < 2; qi++)
      af[qi] = *(const bfrag8*)(&lA[buf][(lg * 64 + wr * 32 + qi * 16 + lr) * 8]);
#pragma unroll
    for (int nj = 0; nj < 4; nj++)
      bfr[nj] = *(const bfrag8*)(&lB[buf][(lg * 128 + wc * 64 + nj * 16 + lr) * 8]);
#pragma unroll
    for (int qi = 0; qi < 2; qi++)
#pragma unroll
      for (int nj = 0; nj < 4; nj++)
        acc[qi][nj] = __builtin_amdgcn_mfma_f32_16x16x32_bf16(af[qi], bfr[nj], acc[qi][nj], 0, 0, 0);
    __syncthreads();
  }

#pragma unroll
  for (int qi = 0; qi < 2; qi++)
#pragma unroll
    for (int nj = 0; nj < 4; nj++) {
      int m0 = mBase + wr * 32 + qi * 16 + lg * 4;
      int o = nBase + wc * 64 + nj * 16 + lr;
      float bv = bias[o];
#pragma unroll
      for (int r = 0; r < 4; r++) {
        float v = acc[qi][nj][r] + bv;
        int mm = m0 + r;
        if (MODE == 0) {
          int n = mm >> 2, g = mm & 3;
          int chunk = o >> 9, cc = o & 511, h = cc >> 5, d = cc & 31;
          size_t oidx = ((size_t)(g * 16 + h) * 1024 + n) * 32 + d;
          if (chunk == 0)      oQ[oidx] = f2bf(v * SCALING);
          else if (chunk == 1) oK[oidx] = f2bf(v);
          else                 oV[oidx] = f2bf(v);
        } else {
          oF[(size_t)mm * 512 + o] = v;
        }
      }
    }
}

// ---------------------------------------------------------------------------
// Kernel 3: V [gh][n][32] -> Vt [gh][32][n]   (grid 64 x 4, 256-row tiles)
// ---------------------------------------------------------------------------
__global__ __launch_bounds__(256)
void transpose_v(const unsigned short* __restrict__ V, unsigned short* __restrict__ Vt) {
  __shared__ unsigned short tile[32][264];
  const int gh = blockIdx.x, n0 = blockIdx.y * 256;
  const int t = threadIdx.x;
  const unsigned short* src = V + ((size_t)gh * 1024 + n0) * 32;
#pragma unroll
  for (int c = 0; c < 4; c++) {
    int j = c * 256 + t; int row = j >> 2, d0 = (j & 3) * 8;
    bfrag8 v = *(const bfrag8*)(src + (size_t)row * 32 + d0);
#pragma unroll
    for (int i = 0; i < 8; i++) tile[d0 + i][row] = (unsigned short)v[i];
  }
  __syncthreads();
  unsigned short* dst = Vt + (size_t)gh * 32 * 1024 + n0;
#pragma unroll
  for (int c = 0; c < 4; c++) {
    int j = c * 256 + t; int d = j >> 5, n8 = (j & 31) * 8;
    *(bfrag8*)(dst + (size_t)d * 1024 + n8) = *(const bfrag8*)(&tile[d][n8]);
  }
}

// ---------------------------------------------------------------------------
// Kernel 4: fused flash attention — round-5: TRANSPOSED SCORE TILE.
// Split-K reverted (regressed). Single structural change vs round 3:
// compute S^T = mfma(kf, qf, bias^T) instead of mfma(qf, kf, bias).
// A/B fragment layouts of 16x16x32 are structurally identical, so the qf/kf
// loads are untouched; only the C/D interpretation flips:
//  * C operand: lane needs bias[q=lr][k = lg*4+r] -> 4 CONSECUTIVE floats
//    -> one global_load_dwordx4 per j. 16 VMEM -> 4 VMEM per iteration.
//  * D: lane holds 16 k-values of ONE q-row -> softmax reduction is 15
//    in-register ops + shfl_xor(16) + shfl_xor(32). 32 shuffles -> 8.
//  * P store: 4 consecutive k per lane -> pack 4 bf16 -> 4x ds_write_b64
//    (was 16x ds_write_b16). PV side unchanged (same swizzled LDS layout).
//  * softmax state (m, l, scale) is scalar per lane -> ~55 VGPR live set,
//    fits the allocator's 64 budget with margin (no spills).
// ---------------------------------------------------------------------------
__global__ __launch_bounds__(256)
void attn_kernel(const unsigned short* __restrict__ Qs, const unsigned short* __restrict__ Ks,
                 const unsigned short* __restrict__ Vt, const float* __restrict__ biasG,
                 unsigned short* __restrict__ Out) {
  __shared__ __align__(16) unsigned short Pl[4][16 * 64];   // 8 KB, per-wave P tile
  const int gh = blockIdx.x, q0 = blockIdx.y * 64;
  const int t = threadIdx.x, w = t >> 6, l = t & 63;
  const int lr = l & 15, lg = l >> 4;

  const unsigned short* Qg = Qs + (size_t)gh * 1024 * 32;
  const unsigned short* Kg = Ks + (size_t)gh * 1024 * 32;
  const unsigned short* Vg = Vt + (size_t)gh * 32 * 1024;
  // this lane's bias row (q = q0 + w*16 + lr), cols indexed by k
  const float* Bq = biasG + (size_t)gh * 1048576 + (size_t)(q0 + w * 16 + lr) * 1024;

  bfrag8 qf = *(const bfrag8*)(Qg + (size_t)(q0 + w * 16 + lr) * 32 + lg * 8);

  facc4 accO[2];
  accO[0] = (facc4){0.f, 0.f, 0.f, 0.f};
  accO[1] = (facc4){0.f, 0.f, 0.f, 0.f};
  float mrun = -3.0e38f, lrun = 0.f;

  unsigned short* Pw = Pl[w];

#pragma unroll 1
  for (int kt = 0; kt < 16; kt++) {
    const int kb = kt * 64;
    // bias^T -> MFMA C operand: float4 per j (consecutive k for this lane)
    facc4 sc[4];
#pragma unroll
    for (int j = 0; j < 4; j++)
      sc[j] = *(const facc4*)(Bq + kb + j * 16 + lg * 4);
    // S^T = K·Q^T + bias^T   (swapped operands; same qf/kf fragments)
#pragma unroll
    for (int j = 0; j < 4; j++) {
      bfrag8 kf = *(const bfrag8*)(Kg + (size_t)(kb + j * 16 + lr) * 32 + lg * 8);
      sc[j] = __builtin_amdgcn_mfma_f32_16x16x32_bf16(kf, qf, sc[j], 0, 0, 0);
    }
    // tile max: 16 in-lane values (one q-row slice) + 2 cross-lane steps
    float tm = sc[0][0];
#pragma unroll
    for (int j = 0; j < 4; j++)
#pragma unroll
      for (int r = 0; r < 4; r++) tm = fmaxf(tm, sc[j][r]);
    tm = fmaxf(tm, __shfl_xor(tm, 16, 64));
    tm = fmaxf(tm, __shfl_xor(tm, 32, 64));
    // online softmax update (scalar state per lane)
    float mn = fmaxf(mrun, tm);
    float scale = __expf(mrun - mn);
    mrun = mn;
    float rs = 0.f;
    uint2 pk[4];
#pragma unroll
    for (int j = 0; j < 4; j++) {
      float p0 = __expf(sc[j][0] - mn);
      float p1 = __expf(sc[j][1] - mn);
      float p2 = __expf(sc[j][2] - mn);
      float p3 = __expf(sc[j][3] - mn);
      rs += (p0 + p1) + (p2 + p3);
      pk[j].x = (unsigned)f2bf(p0) | ((unsigned)f2bf(p1) << 16);
      pk[j].y = (unsigned)f2bf(p2) | ((unsigned)f2bf(p3) << 16);
    }
    rs += __shfl_xor(rs, 16, 64);
    rs += __shfl_xor(rs, 32, 64);
    lrun = lrun * scale + rs;
    // P^T -> LDS P[q][k] rows: lane writes 8B (4 consecutive k) per j
#pragma unroll
    for (int j = 0; j < 4; j++) {
      int byte = (lr * 128 + j * 32 + lg * 8) ^ ((lr & 7) << 4);
      *(uint2*)((char*)Pw + byte) = pk[j];
    }
    // redistribute scale to PV's row layout (q = lg*4 + r)
    float sc_pv[4];
#pragma unroll
    for (int r = 0; r < 4; r++) sc_pv[r] = __shfl(scale, lg * 4 + r, 64);
#pragma unroll
    for (int h = 0; h < 2; h++)
#pragma unroll
      for (int r = 0; r < 4; r++) accO[h][r] *= sc_pv[r];
    // PV (unchanged: P A-frags from own-wave LDS; V B-frags from Vt)
#pragma unroll
    for (int ksb = 0; ksb < 2; ksb++) {
      int byte = (lr * 128 + ksb * 64 + lg * 16) ^ ((lr & 7) << 4);
      bfrag8 pf = *(const bfrag8*)((char*)Pw + byte);
#pragma unroll
      for (int h = 0; h < 2; h++) {
        bfrag8 vf = *(const bfrag8*)(Vg + (size_t)(h * 16 + lr) * 1024 + kb + ksb * 32 + lg * 8);
        accO[h] = __builtin_amdgcn_mfma_f32_16x16x32_bf16(pf, vf, accO[h], 0, 0, 0);
      }
    }
  }

  // epilogue: O / l  -> attn_out bf16 [4096, 512]  (lrun lives at lane q=lr)
  float lr_pv[4];
#pragma unroll
  for (int r = 0; r < 4; r++) lr_pv[r] = __shfl(lrun, lg * 4 + r, 64);
  const int g = gh >> 4, hh = gh & 15;
#pragma unroll
  for (int h = 0; h < 2; h++)
#pragma unroll
    for (int r = 0; r < 4; r++) {
      int q = q0 + w * 16 + lg * 4 + r;
      float v = accO[h][r] / lr_pv[r];
      int e = hh * 32 + h * 16 + lr;
      Out[(size_t)(q * 4 + g) * 512 + e] = f2bf(v);
    }
}

// ---------------------------------------------------------------------------
extern "C" void kernel_launch(void* const* d_in, const int* in_sizes, int n_in,
                              void* d_out, int out_size, void* d_ws, size_t ws_size,
                              hipStream_t stream) {
  (void)in_sizes; (void)n_in; (void)out_size; (void)ws_size;
  const float* query = (const float*)d_in[0];
  const float* abias = (const float*)d_in[1];
  const float* W_in  = (const float*)d_in[2];
  const float* b_in  = (const float*)d_in[3];
  const float* W_out = (const float*)d_in[4];
  const float* b_out = (const float*)d_in[5];
  float* out = (float*)d_out;
  char* ws = (char*)d_ws;
  unsigned short* qbf  = (unsigned short*)(ws);             // 4 MB
  unsigned short* wibf = (unsigned short*)(ws + 4194304);   // 1.5 MB
  unsigned short* wobf = (unsigned short*)(ws + 5767168);   // 0.5 MB
  unsigned short* Qs   = (unsigned short*)(ws + 6291456);   // 4 MB  [gh][n][d]
  unsigned short* Ks   = (unsigned short*)(ws + 10485760);  // 4 MB  [gh][n][d]
  unsigned short* Vv   = (unsigned short*)(ws + 14680064);  // 4 MB  [gh][n][d]
  unsigned short* Vt   = (unsigned short*)(ws + 18874368);  // 4 MB  [gh][d][n]
  unsigned short* attO = (unsigned short*)(ws + 23068672);  // 4 MB  [m][e]

  convert_bf16<<<3072, 256, 0, stream>>>(query, W_in, W_out, qbf, wibf, wobf);
  gemm_bt<0><<<dim3(64, 12), 256, 0, stream>>>(qbf, wibf, b_in, Qs, Ks, Vv, nullptr);
  transpose_v<<<dim3(64, 4), 256, 0, stream>>>(Vv, Vt);
  attn_kernel<<<dim3(64, 16), 256, 0, stream>>>(Qs, Ks, Vt, abias, attO);
  gemm_bt<1><<<dim3(64, 4), 256, 0, stream>>>(attO, wobf, b_out, nullptr, nullptr, nullptr, out);
}

// Round 6
// 127.262 us; speedup vs baseline: 1.0905x; 1.0121x over previous
//
#include <hip/hip_runtime.h>
#include <hip/hip_bf16.h>
#include <stdint.h>
#include <stddef.h>

// ---------- types ----------
typedef __attribute__((ext_vector_type(8))) short bfrag8;   // 8 bf16 in 4 VGPRs
typedef __attribute__((ext_vector_type(4))) float facc4;    // MFMA accumulator

#define SCALING 0.17677669529663687f   // 32^-0.5

__device__ __forceinline__ unsigned short f2bf(float f) {
  union { float f; unsigned u; } v; v.f = f;
  unsigned r = v.u + 0x7fffu + ((v.u >> 16) & 1u);   // RNE
  return (unsigned short)(r >> 16);
}

// ---------------------------------------------------------------------------
// Kernel 1: fp32 -> bf16 convert for query, W_in, W_out
// ---------------------------------------------------------------------------
__global__ __launch_bounds__(256)
void convert_bf16(const float* __restrict__ q, const float* __restrict__ wi,
                  const float* __restrict__ wo,
                  unsigned short* __restrict__ qb, unsigned short* __restrict__ wib,
                  unsigned short* __restrict__ wob) {
  int t = blockIdx.x * 256 + threadIdx.x;
  const float4* src; unsigned short* dst; int idx;
  if (t < 524288)            { src = (const float4*)q;  dst = qb;  idx = t; }
  else if (t < 524288+196608){ src = (const float4*)wi; dst = wib; idx = t - 524288; }
  else                       { src = (const float4*)wo; dst = wob; idx = t - 720896; }
  float4 v = src[idx];
  ushort4 o;
  o.x = f2bf(v.x); o.y = f2bf(v.y); o.z = f2bf(v.z); o.w = f2bf(v.w);
  *(ushort4*)(dst + (size_t)idx * 4) = o;
}

// ---------------------------------------------------------------------------
// Kernel 2/5: GEMM  C[M x N] = A[M x 512] * B[N x 512]^T
// MODE 0: qkv epilogue; MODE 1: out epilogue
// ---------------------------------------------------------------------------
template<int MODE>
__global__ __launch_bounds__(256, 2)
void gemm_bt(const unsigned short* __restrict__ A, const unsigned short* __restrict__ Bw,
             const float* __restrict__ bias,
             unsigned short* __restrict__ oQ, unsigned short* __restrict__ oK,
             unsigned short* __restrict__ oV, float* __restrict__ oF) {
  constexpr int K = 512;
  __shared__ __align__(16) unsigned short lA[2][64 * 32];
  __shared__ __align__(16) unsigned short lB[2][128 * 32];
  const int t = threadIdx.x;
  const int w = t >> 6, l = t & 63;
  const int lr = l & 15, lg = l >> 4;
  const int mBase = blockIdx.x * 64;
  const int nBase = blockIdx.y * 128;
  const int wr = w >> 1, wc = w & 1;

  facc4 acc[2][4];
#pragma unroll
  for (int i = 0; i < 2; i++)
#pragma unroll
    for (int j = 0; j < 4; j++) acc[i][j] = (facc4){0.f, 0.f, 0.f, 0.f};

  const int arow = t & 63, aslot = t >> 6;
  const unsigned short* aSrc = A + (size_t)(mBase + arow) * K + aslot * 8;
  const int bcol0 = t & 127, bslot0 = t >> 7;
  const int bcol1 = (256 + t) & 127, bslot1 = (256 + t) >> 7;
  const unsigned short* bSrc0 = Bw + (size_t)(nBase + bcol0) * K + bslot0 * 8;
  const unsigned short* bSrc1 = Bw + (size_t)(nBase + bcol1) * K + bslot1 * 8;

  auto stage = [&](int ks, int buf) {
    const int kB = ks * 32;
    *(int4*)(&lA[buf][(size_t)t * 8])         = *(const int4*)(aSrc + kB);
    *(int4*)(&lB[buf][(size_t)t * 8])         = *(const int4*)(bSrc0 + kB);
    *(int4*)(&lB[buf][(size_t)(256 + t) * 8]) = *(const int4*)(bSrc1 + kB);
  };

  stage(0, 0);
  __syncthreads();
#pragma unroll 1
  for (int ks = 0; ks < 16; ks++) {
    const int buf = ks & 1;
    if (ks < 15) stage(ks + 1, buf ^ 1);
    bfrag8 af[2], bfr[4];
#pragma unroll
    for (int qi = 0; qi < 2; qi++)
      af[qi] = *(const bfrag8*)(&lA[buf][(lg * 64 + wr * 32 + qi * 16 + lr) * 8]);
#pragma unroll
    for (int nj = 0; nj < 4; nj++)
      bfr[nj] = *(const bfrag8*)(&lB[buf][(lg * 128 + wc * 64 + nj * 16 + lr) * 8]);
#pragma unroll
    for (int qi = 0; qi < 2; qi++)
#pragma unroll
      for (int nj = 0; nj < 4; nj++)
        acc[qi][nj] = __builtin_amdgcn_mfma_f32_16x16x32_bf16(af[qi], bfr[nj], acc[qi][nj], 0, 0, 0);
    __syncthreads();
  }

#pragma unroll
  for (int qi = 0; qi < 2; qi++)
#pragma unroll
    for (int nj = 0; nj < 4; nj++) {
      int m0 = mBase + wr * 32 + qi * 16 + lg * 4;
      int o = nBase + wc * 64 + nj * 16 + lr;
      float bv = bias[o];
#pragma unroll
      for (int r = 0; r < 4; r++) {
        float v = acc[qi][nj][r] + bv;
        int mm = m0 + r;
        if (MODE == 0) {
          int n = mm >> 2, g = mm & 3;
          int chunk = o >> 9, cc = o & 511, h = cc >> 5, d = cc & 31;
          size_t oidx = ((size_t)(g * 16 + h) * 1024 + n) * 32 + d;
          if (chunk == 0)      oQ[oidx] = f2bf(v * SCALING);
          else if (chunk == 1) oK[oidx] = f2bf(v);
          else                 oV[oidx] = f2bf(v);
        } else {
          oF[(size_t)mm * 512 + o] = v;
        }
      }
    }
}

// ---------------------------------------------------------------------------
// Kernel 3: V [gh][n][32] -> Vt [gh][32][n]   (grid 64 x 4, 256-row tiles)
// ---------------------------------------------------------------------------
__global__ __launch_bounds__(256)
void transpose_v(const unsigned short* __restrict__ V, unsigned short* __restrict__ Vt) {
  __shared__ unsigned short tile[32][264];
  const int gh = blockIdx.x, n0 = blockIdx.y * 256;
  const int t = threadIdx.x;
  const unsigned short* src = V + ((size_t)gh * 1024 + n0) * 32;
#pragma unroll
  for (int c = 0; c < 4; c++) {
    int j = c * 256 + t; int row = j >> 2, d0 = (j & 3) * 8;
    bfrag8 v = *(const bfrag8*)(src + (size_t)row * 32 + d0);
#pragma unroll
    for (int i = 0; i < 8; i++) tile[d0 + i][row] = (unsigned short)v[i];
  }
  __syncthreads();
  unsigned short* dst = Vt + (size_t)gh * 32 * 1024 + n0;
#pragma unroll
  for (int c = 0; c < 4; c++) {
    int j = c * 256 + t; int d = j >> 5, n8 = (j & 31) * 8;
    *(bfrag8*)(dst + (size_t)d * 1024 + n8) = *(const bfrag8*)(&tile[d][n8]);
  }
}

// ---------------------------------------------------------------------------
// Kernel 4: fused flash attention — round-6: 1-DEEP BIAS PIPELINE VIA LDS.
//
// Rounds 4/5 taught: the limiter is the serial bias-load -> MFMA-C-operand
// chain (loads drain immediately at their use; wave duty cycle ~45% -> 2.5
// TB/s observed). Fix: global_load_lds stages tile kt+1 into a PER-WAVE
// 4 KB LDS double-buffer while tile kt computes; loads stay in flight a
// full iteration. Zero VGPR cost (register prefetch = rounds 1-2 spill
// disaster). Wave-private buffers -> no barriers; one asm vmcnt(0) at loop
// top waits only on loads issued one iteration ago.
//
// LDS dest of global_load_lds is linear (lane*16B); the bank swizzle
// (col^=(row&7) at 16B granularity) is applied by PRE-SWIZZLING the global
// source column per lane, so the ds_read_b128 side spreads 8 bank-quads.
// LDS total = 32 KB bias + 8 KB P = 40 KB -> exactly 4 blocks/CU.
// ---------------------------------------------------------------------------
__global__ __launch_bounds__(256)
void attn_kernel(const unsigned short* __restrict__ Qs, const unsigned short* __restrict__ Ks,
                 const unsigned short* __restrict__ Vt, const float* __restrict__ biasG,
                 unsigned short* __restrict__ Out) {
  __shared__ __align__(16) float biasL[4][2][16 * 64];      // 32 KB: per-wave dbuf
  __shared__ __align__(16) unsigned short Pl[4][16 * 64];   // 8 KB, per-wave P tile
  const int gh = blockIdx.x, q0 = blockIdx.y * 64;
  const int t = threadIdx.x, w = t >> 6, l = t & 63;
  const int lr = l & 15, lg = l >> 4;

  const unsigned short* Qg = Qs + (size_t)gh * 1024 * 32;
  const unsigned short* Kg = Ks + (size_t)gh * 1024 * 32;
  const unsigned short* Vg = Vt + (size_t)gh * 32 * 1024;
  // bias rows for this wave: q = q0 + w*16 + rl, rl = 0..15
  const float* Bw = biasG + (size_t)gh * 1048576 + (size_t)(q0 + w * 16) * 1024;

  // staging geometry (per call c=0..3): lane l covers row rl = c*4 + (l>>4),
  // swizzled col group cc = (l&15) ^ (rl&7)  -> global col cc*4 .. +3.
  // LDS slot = c*1024B + l*16B  ==> linear row-major [16][64] f32 with the
  // read-side XOR  byte = rl*256 + ((col*4) ^ ((rl&7)<<4)).
  const int rl_base = (l >> 4);              // +4*c
  const int ccx = (l & 15);

  bfrag8 qf = *(const bfrag8*)(Qg + (size_t)(q0 + w * 16 + lr) * 32 + lg * 8);

  facc4 accO[2];
  accO[0] = (facc4){0.f, 0.f, 0.f, 0.f};
  accO[1] = (facc4){0.f, 0.f, 0.f, 0.f};
  float mrun = -3.0e38f, lrun = 0.f;

  unsigned short* Pw = Pl[w];

  auto stageBias = [&](int kb, int buf) {
#pragma unroll
    for (int c = 0; c < 4; c++) {
      int rl = c * 4 + rl_base;
      int cc = ccx ^ (rl & 7);
      __builtin_amdgcn_global_load_lds(
          (const __attribute__((address_space(1))) unsigned int*)(Bw + (size_t)rl * 1024 + kb + cc * 4),
          (__attribute__((address_space(3))) unsigned int*)(&biasL[w][buf][c * 256]),
          16, 0, 0);
    }
  };

  stageBias(0, 0);

#pragma unroll 1
  for (int kt = 0; kt < 16; kt++) {
    const int kb = kt * 64;
    const int buf = kt & 1;
    // wait for bias tile kt (issued one full iteration ago); memory clobber
    // pins the following ds_reads below this point
    asm volatile("s_waitcnt vmcnt(0)" ::: "memory");
    // bias^T from LDS -> MFMA C operand (float4 per j, bank-swizzled)
    facc4 sc[4];
    const char* bL = (const char*)&biasL[w][buf][0];
#pragma unroll
    for (int j = 0; j < 4; j++) {
      int bo = lr * 256 + ((j * 64 + lg * 16) ^ ((lr & 7) << 4));
      sc[j] = *(const facc4*)(bL + bo);
    }
    // issue next tile's staging NOW — in flight across softmax + PV
    if (kt < 15) stageBias(kb + 64, buf ^ 1);
    // S^T = K·Q^T + bias^T   (swapped operands)
#pragma unroll
    for (int j = 0; j < 4; j++) {
      bfrag8 kf = *(const bfrag8*)(Kg + (size_t)(kb + j * 16 + lr) * 32 + lg * 8);
      sc[j] = __builtin_amdgcn_mfma_f32_16x16x32_bf16(kf, qf, sc[j], 0, 0, 0);
    }
    // tile max: 16 in-lane values + 2 cross-lane steps
    float tm = sc[0][0];
#pragma unroll
    for (int j = 0; j < 4; j++)
#pragma unroll
      for (int r = 0; r < 4; r++) tm = fmaxf(tm, sc[j][r]);
    tm = fmaxf(tm, __shfl_xor(tm, 16, 64));
    tm = fmaxf(tm, __shfl_xor(tm, 32, 64));
    // online softmax update (scalar state per lane)
    float mn = fmaxf(mrun, tm);
    float scale = __expf(mrun - mn);
    mrun = mn;
    float rs = 0.f;
    uint2 pk[4];
#pragma unroll
    for (int j = 0; j < 4; j++) {
      float p0 = __expf(sc[j][0] - mn);
      float p1 = __expf(sc[j][1] - mn);
      float p2 = __expf(sc[j][2] - mn);
      float p3 = __expf(sc[j][3] - mn);
      rs += (p0 + p1) + (p2 + p3);
      pk[j].x = (unsigned)f2bf(p0) | ((unsigned)f2bf(p1) << 16);
      pk[j].y = (unsigned)f2bf(p2) | ((unsigned)f2bf(p3) << 16);
    }
    rs += __shfl_xor(rs, 16, 64);
    rs += __shfl_xor(rs, 32, 64);
    lrun = lrun * scale + rs;
    // P^T -> LDS P[q][k] rows: lane writes 8B (4 consecutive k) per j
#pragma unroll
    for (int j = 0; j < 4; j++) {
      int byte = (lr * 128 + j * 32 + lg * 8) ^ ((lr & 7) << 4);
      *(uint2*)((char*)Pw + byte) = pk[j];
    }
    // redistribute scale to PV's row layout (q = lg*4 + r)
    float sc_pv[4];
#pragma unroll
    for (int r = 0; r < 4; r++) sc_pv[r] = __shfl(scale, lg * 4 + r, 64);
#pragma unroll
    for (int h = 0; h < 2; h++)
#pragma unroll
      for (int r = 0; r < 4; r++) accO[h][r] *= sc_pv[r];
    // PV (P A-frags from own-wave LDS; V B-frags from Vt)
#pragma unroll
    for (int ksb = 0; ksb < 2; ksb++) {
      int byte = (lr * 128 + ksb * 64 + lg * 16) ^ ((lr & 7) << 4);
      bfrag8 pf = *(const bfrag8*)((char*)Pw + byte);
#pragma unroll
      for (int h = 0; h < 2; h++) {
        bfrag8 vf = *(const bfrag8*)(Vg + (size_t)(h * 16 + lr) * 1024 + kb + ksb * 32 + lg * 8);
        accO[h] = __builtin_amdgcn_mfma_f32_16x16x32_bf16(pf, vf, accO[h], 0, 0, 0);
      }
    }
  }

  // epilogue: O / l  -> attn_out bf16 [4096, 512]  (lrun lives at lane q=lr)
  float lr_pv[4];
#pragma unroll
  for (int r = 0; r < 4; r++) lr_pv[r] = __shfl(lrun, lg * 4 + r, 64);
  const int g = gh >> 4, hh = gh & 15;
#pragma unroll
  for (int h = 0; h < 2; h++)
#pragma unroll
    for (int r = 0; r < 4; r++) {
      int q = q0 + w * 16 + lg * 4 + r;
      float v = accO[h][r] / lr_pv[r];
      int e = hh * 32 + h * 16 + lr;
      Out[(size_t)(q * 4 + g) * 512 + e] = f2bf(v);
    }
}

// ---------------------------------------------------------------------------
extern "C" void kernel_launch(void* const* d_in, const int* in_sizes, int n_in,
                              void* d_out, int out_size, void* d_ws, size_t ws_size,
                              hipStream_t stream) {
  (void)in_sizes; (void)n_in; (void)out_size; (void)ws_size;
  const float* query = (const float*)d_in[0];
  const float* abias = (const float*)d_in[1];
  const float* W_in  = (const float*)d_in[2];
  const float* b_in  = (const float*)d_in[3];
  const float* W_out = (const float*)d_in[4];
  const float* b_out = (const float*)d_in[5];
  float* out = (float*)d_out;
  char* ws = (char*)d_ws;
  unsigned short* qbf  = (unsigned short*)(ws);             // 4 MB
  unsigned short* wibf = (unsigned short*)(ws + 4194304);   // 1.5 MB
  unsigned short* wobf = (unsigned short*)(ws + 5767168);   // 0.5 MB
  unsigned short* Qs   = (unsigned short*)(ws + 6291456);   // 4 MB  [gh][n][d]
  unsigned short* Ks   = (unsigned short*)(ws + 10485760);  // 4 MB  [gh][n][d]
  unsigned short* Vv   = (unsigned short*)(ws + 14680064);  // 4 MB  [gh][n][d]
  unsigned short* Vt   = (unsigned short*)(ws + 18874368);  // 4 MB  [gh][d][n]
  unsigned short* attO = (unsigned short*)(ws + 23068672);  // 4 MB  [m][e]

  convert_bf16<<<3072, 256, 0, stream>>>(query, W_in, W_out, qbf, wibf, wobf);
  gemm_bt<0><<<dim3(64, 12), 256, 0, stream>>>(qbf, wibf, b_in, Qs, Ks, Vv, nullptr);
  transpose_v<<<dim3(64, 4), 256, 0, stream>>>(Vv, Vt);
  attn_kernel<<<dim3(64, 16), 256, 0, stream>>>(Qs, Ks, Vt, abias, attO);
  gemm_bt<1><<<dim3(64, 4), 256, 0, stream>>>(attO, wobf, b_out, nullptr, nullptr, nullptr, out);
}

// Round 7
// 124.066 us; speedup vs baseline: 1.1186x; 1.0258x over previous
//
#include <hip/hip_runtime.h>
#include <hip/hip_bf16.h>
#include <stdint.h>
#include <stddef.h>

// ---------- types ----------
typedef __attribute__((ext_vector_type(8))) short bfrag8;   // 8 bf16 in 4 VGPRs
typedef __attribute__((ext_vector_type(4))) float facc4;    // MFMA accumulator

#define SCALING 0.17677669529663687f   // 32^-0.5

__device__ __forceinline__ unsigned short f2bf(float f) {
  union { float f; unsigned u; } v; v.f = f;
  unsigned r = v.u + 0x7fffu + ((v.u >> 16) & 1u);   // RNE
  return (unsigned short)(r >> 16);
}

// ---------------------------------------------------------------------------
// Kernel 1: fp32 -> bf16 convert for query, W_in, W_out
// ---------------------------------------------------------------------------
__global__ __launch_bounds__(256)
void convert_bf16(const float* __restrict__ q, const float* __restrict__ wi,
                  const float* __restrict__ wo,
                  unsigned short* __restrict__ qb, unsigned short* __restrict__ wib,
                  unsigned short* __restrict__ wob) {
  int t = blockIdx.x * 256 + threadIdx.x;
  const float4* src; unsigned short* dst; int idx;
  if (t < 524288)            { src = (const float4*)q;  dst = qb;  idx = t; }
  else if (t < 524288+196608){ src = (const float4*)wi; dst = wib; idx = t - 524288; }
  else                       { src = (const float4*)wo; dst = wob; idx = t - 720896; }
  float4 v = src[idx];
  ushort4 o;
  o.x = f2bf(v.x); o.y = f2bf(v.y); o.z = f2bf(v.z); o.w = f2bf(v.w);
  *(ushort4*)(dst + (size_t)idx * 4) = o;
}

// ---------------------------------------------------------------------------
// Kernel 2/5: GEMM  C[M x N] = A[M x 512] * B[N x 512]^T  (both K-contiguous)
// BM=64, BN=128, BK=32, 256 threads (4 waves in 2x2), wave tile 32x64.
// MODE 0: qkv epilogue (+b_in, scale q, scatter to Qs/Ks/V [gh][n][d])
// MODE 1: out epilogue (+b_out, fp32 store to d_out)
// ---------------------------------------------------------------------------
template<int MODE>
__global__ __launch_bounds__(256, 2)
void gemm_bt(const unsigned short* __restrict__ A, const unsigned short* __restrict__ Bw,
             const float* __restrict__ bias,
             unsigned short* __restrict__ oQ, unsigned short* __restrict__ oK,
             unsigned short* __restrict__ oV, float* __restrict__ oF) {
  constexpr int K = 512;
  __shared__ __align__(16) unsigned short lA[2][64 * 32];
  __shared__ __align__(16) unsigned short lB[2][128 * 32];
  const int t = threadIdx.x;
  const int w = t >> 6, l = t & 63;
  const int lr = l & 15, lg = l >> 4;
  const int mBase = blockIdx.x * 64;
  const int nBase = blockIdx.y * 128;
  const int wr = w >> 1, wc = w & 1;

  facc4 acc[2][4];
#pragma unroll
  for (int i = 0; i < 2; i++)
#pragma unroll
    for (int j = 0; j < 4; j++) acc[i][j] = (facc4){0.f, 0.f, 0.f, 0.f};

  const int arow = t & 63, aslot = t >> 6;
  const unsigned short* aSrc = A + (size_t)(mBase + arow) * K + aslot * 8;
  const int bcol0 = t & 127, bslot0 = t >> 7;
  const int bcol1 = (256 + t) & 127, bslot1 = (256 + t) >> 7;
  const unsigned short* bSrc0 = Bw + (size_t)(nBase + bcol0) * K + bslot0 * 8;
  const unsigned short* bSrc1 = Bw + (size_t)(nBase + bcol1) * K + bslot1 * 8;

  auto stage = [&](int ks, int buf) {
    const int kB = ks * 32;
    *(int4*)(&lA[buf][(size_t)t * 8])         = *(const int4*)(aSrc + kB);
    *(int4*)(&lB[buf][(size_t)t * 8])         = *(const int4*)(bSrc0 + kB);
    *(int4*)(&lB[buf][(size_t)(256 + t) * 8]) = *(const int4*)(bSrc1 + kB);
  };

  stage(0, 0);
  __syncthreads();
#pragma unroll 1
  for (int ks = 0; ks < 16; ks++) {
    const int buf = ks & 1;
    if (ks < 15) stage(ks + 1, buf ^ 1);
    bfrag8 af[2], bfr[4];
#pragma unroll
    for (int qi = 0; qi < 2; qi++)
      af[qi] = *(const bfrag8*)(&lA[buf][(lg * 64 + wr * 32 + qi * 16 + lr) * 8]);
#pragma unroll
    for (int nj = 0; nj < 4; nj++)
      bfr[nj] = *(const bfrag8*)(&lB[buf][(lg * 128 + wc * 64 + nj * 16 + lr) * 8]);
#pragma unroll
    for (int qi = 0; qi < 2; qi++)
#pragma unroll
      for (int nj = 0; nj < 4; nj++)
        acc[qi][nj] = __builtin_amdgcn_mfma_f32_16x16x32_bf16(af[qi], bfr[nj], acc[qi][nj], 0, 0, 0);
    __syncthreads();
  }

#pragma unroll
  for (int qi = 0; qi < 2; qi++)
#pragma unroll
    for (int nj = 0; nj < 4; nj++) {
      int m0 = mBase + wr * 32 + qi * 16 + lg * 4;
      int o = nBase + wc * 64 + nj * 16 + lr;
      float bv = bias[o];
#pragma unroll
      for (int r = 0; r < 4; r++) {
        float v = acc[qi][nj][r] + bv;
        int mm = m0 + r;
        if (MODE == 0) {
          int n = mm >> 2, g = mm & 3;
          int chunk = o >> 9, cc = o & 511, h = cc >> 5, d = cc & 31;
          size_t oidx = ((size_t)(g * 16 + h) * 1024 + n) * 32 + d;
          if (chunk == 0)      oQ[oidx] = f2bf(v * SCALING);
          else if (chunk == 1) oK[oidx] = f2bf(v);
          else                 oV[oidx] = f2bf(v);
        } else {
          oF[(size_t)mm * 512 + o] = v;
        }
      }
    }
}

// ---------------------------------------------------------------------------
// Kernel 3: V [gh][n][32] -> Vt [gh][32][n]   (grid 64 x 4, 256-row tiles)
// ---------------------------------------------------------------------------
__global__ __launch_bounds__(256)
void transpose_v(const unsigned short* __restrict__ V, unsigned short* __restrict__ Vt) {
  __shared__ unsigned short tile[32][264];
  const int gh = blockIdx.x, n0 = blockIdx.y * 256;
  const int t = threadIdx.x;
  const unsigned short* src = V + ((size_t)gh * 1024 + n0) * 32;
#pragma unroll
  for (int c = 0; c < 4; c++) {
    int j = c * 256 + t; int row = j >> 2, d0 = (j & 3) * 8;
    bfrag8 v = *(const bfrag8*)(src + (size_t)row * 32 + d0);
#pragma unroll
    for (int i = 0; i < 8; i++) tile[d0 + i][row] = (unsigned short)v[i];
  }
  __syncthreads();
  unsigned short* dst = Vt + (size_t)gh * 32 * 1024 + n0;
#pragma unroll
  for (int c = 0; c < 4; c++) {
    int j = c * 256 + t; int d = j >> 5, n8 = (j & 31) * 8;
    *(bfrag8*)(dst + (size_t)d * 1024 + n8) = *(const bfrag8*)(&tile[d][n8]);
  }
}

// ---------------------------------------------------------------------------
// Kernel 4: fused flash attention — round-7: K-TILE STAGGER.
// Exact round-3 kernel (best measured: 122.5 total) + ONE change: block
// (gh,qt) starts its K-loop at kt0 = (gh+qt)&15 and wraps (online softmax is
// K-order-invariant).
// WHY: r3/r5/r6 attn variants (scalar loads / transposed tile / LDS pipeline)
// all land ~105 us => bottleneck is not instruction count or pipeline depth.
// Address arithmetic: at tile kt every block reads 256 B segments at 4 KB
// stride => row stride = 16 HBM granules => only 2-4 channels active, and all
// 1024 blocks sweep kt=0..15 in LOCKSTEP so the whole GPU hammers the same
// channels simultaneously (~2.5 TB/s observed cap). The stagger spreads
// concurrently-active blocks uniformly over all 16 column-blocks -> all
// channels busy.
// ---------------------------------------------------------------------------
__global__ __launch_bounds__(256)
void attn_kernel(const unsigned short* __restrict__ Qs, const unsigned short* __restrict__ Ks,
                 const unsigned short* __restrict__ Vt, const float* __restrict__ biasG,
                 unsigned short* __restrict__ Out) {
  __shared__ __align__(16) unsigned short Pl[4][16 * 64];   // 8 KB, per-wave P tile
  const int gh = blockIdx.x, q0 = blockIdx.y * 64;
  const int t = threadIdx.x, w = t >> 6, l = t & 63;
  const int lr = l & 15, lg = l >> 4;

  const unsigned short* Qg = Qs + (size_t)gh * 1024 * 32;
  const unsigned short* Kg = Ks + (size_t)gh * 1024 * 32;
  const unsigned short* Vg = Vt + (size_t)gh * 32 * 1024;
  // per-thread bias base: row = q0 + w*16 + lg*4 (+r), col = lr (+j*16 + kb)
  const float* Bt = biasG + (size_t)gh * 1048576 + (size_t)(q0 + w * 16 + lg * 4) * 1024 + lr;

  bfrag8 qf = *(const bfrag8*)(Qg + (size_t)(q0 + w * 16 + lr) * 32 + lg * 8);

  facc4 accO[2];
  accO[0] = (facc4){0.f, 0.f, 0.f, 0.f};
  accO[1] = (facc4){0.f, 0.f, 0.f, 0.f};
  float mrun[4], lrun[4];
#pragma unroll
  for (int r = 0; r < 4; r++) { mrun[r] = -3.0e38f; lrun[r] = 0.f; }

  unsigned short* Pw = Pl[w];
  const int kt0 = (gh + blockIdx.y) & 15;     // per-block column-phase stagger

#pragma unroll 1
  for (int i = 0; i < 16; i++) {
    const int kt = (kt0 + i) & 15;
    const int kb = kt * 64;
    // bias -> MFMA C operand (16 scalar dword loads, exact C/D lane layout)
    facc4 sc[4];
#pragma unroll
    for (int j = 0; j < 4; j++)
#pragma unroll
      for (int r = 0; r < 4; r++)
        sc[j][r] = Bt[(size_t)r * 1024 + kb + j * 16];
    // QK^T accumulating onto the bias
#pragma unroll
    for (int j = 0; j < 4; j++) {
      bfrag8 kf = *(const bfrag8*)(Kg + (size_t)(kb + j * 16 + lr) * 32 + lg * 8);
      sc[j] = __builtin_amdgcn_mfma_f32_16x16x32_bf16(qf, kf, sc[j], 0, 0, 0);
    }
    // row max over this tile (16-lane column groups)
    float tm[4];
#pragma unroll
    for (int r = 0; r < 4; r++) tm[r] = -3.0e38f;
#pragma unroll
    for (int j = 0; j < 4; j++)
#pragma unroll
      for (int r = 0; r < 4; r++) tm[r] = fmaxf(tm[r], sc[j][r]);
#pragma unroll
    for (int mk = 1; mk < 16; mk <<= 1)
#pragma unroll
      for (int r = 0; r < 4; r++) tm[r] = fmaxf(tm[r], __shfl_xor(tm[r], mk, 64));
    // online softmax update
    float scale[4];
#pragma unroll
    for (int r = 0; r < 4; r++) {
      float mn = fmaxf(mrun[r], tm[r]);
      scale[r] = __expf(mrun[r] - mn);
      mrun[r] = mn;
    }
    float rs[4] = {0.f, 0.f, 0.f, 0.f};
#pragma unroll
    for (int j = 0; j < 4; j++)
#pragma unroll
      for (int r = 0; r < 4; r++) {
        float p = __expf(sc[j][r] - mrun[r]);
        rs[r] += p;
        int row = lg * 4 + r, col = j * 16 + lr;
        int byte = (row * 128 + col * 2) ^ ((row & 7) << 4);
        *(unsigned short*)((char*)Pw + byte) = f2bf(p);
      }
#pragma unroll
    for (int mk = 1; mk < 16; mk <<= 1)
#pragma unroll
      for (int r = 0; r < 4; r++) rs[r] += __shfl_xor(rs[r], mk, 64);
#pragma unroll
    for (int r = 0; r < 4; r++) lrun[r] = lrun[r] * scale[r] + rs[r];
#pragma unroll
    for (int h = 0; h < 2; h++)
#pragma unroll
      for (int r = 0; r < 4; r++) accO[h][r] *= scale[r];
    // PV (P A-frags from own-wave LDS; V B-frags 16B-contiguous from Vt)
#pragma unroll
    for (int ksb = 0; ksb < 2; ksb++) {
      int byte = (lr * 128 + (ksb * 32 + lg * 8) * 2) ^ ((lr & 7) << 4);
      bfrag8 pf = *(const bfrag8*)((char*)Pw + byte);
#pragma unroll
      for (int h = 0; h < 2; h++) {
        bfrag8 vf = *(const bfrag8*)(Vg + (size_t)(h * 16 + lr) * 1024 + kb + ksb * 32 + lg * 8);
        accO[h] = __builtin_amdgcn_mfma_f32_16x16x32_bf16(pf, vf, accO[h], 0, 0, 0);
      }
    }
  }

  // epilogue: O / l  -> attn_out bf16 [4096, 512]
  const int g = gh >> 4, hh = gh & 15;
#pragma unroll
  for (int h = 0; h < 2; h++)
#pragma unroll
    for (int r = 0; r < 4; r++) {
      int q = q0 + w * 16 + lg * 4 + r;
      float v = accO[h][r] / lrun[r];
      int e = hh * 32 + h * 16 + lr;
      Out[(size_t)(q * 4 + g) * 512 + e] = f2bf(v);
    }
}

// ---------------------------------------------------------------------------
extern "C" void kernel_launch(void* const* d_in, const int* in_sizes, int n_in,
                              void* d_out, int out_size, void* d_ws, size_t ws_size,
                              hipStream_t stream) {
  (void)in_sizes; (void)n_in; (void)out_size; (void)ws_size;
  const float* query = (const float*)d_in[0];
  const float* abias = (const float*)d_in[1];
  const float* W_in  = (const float*)d_in[2];
  const float* b_in  = (const float*)d_in[3];
  const float* W_out = (const float*)d_in[4];
  const float* b_out = (const float*)d_in[5];
  float* out = (float*)d_out;
  char* ws = (char*)d_ws;
  unsigned short* qbf  = (unsigned short*)(ws);             // 4 MB
  unsigned short* wibf = (unsigned short*)(ws + 4194304);   // 1.5 MB
  unsigned short* wobf = (unsigned short*)(ws + 5767168);   // 0.5 MB
  unsigned short* Qs   = (unsigned short*)(ws + 6291456);   // 4 MB  [gh][n][d]
  unsigned short* Ks   = (unsigned short*)(ws + 10485760);  // 4 MB  [gh][n][d]
  unsigned short* Vv   = (unsigned short*)(ws + 14680064);  // 4 MB  [gh][n][d]
  unsigned short* Vt   = (unsigned short*)(ws + 18874368);  // 4 MB  [gh][d][n]
  unsigned short* attO = (unsigned short*)(ws + 23068672);  // 4 MB  [m][e]

  convert_bf16<<<3072, 256, 0, stream>>>(query, W_in, W_out, qbf, wibf, wobf);
  gemm_bt<0><<<dim3(64, 12), 256, 0, stream>>>(qbf, wibf, b_in, Qs, Ks, Vv, nullptr);
  transpose_v<<<dim3(64, 4), 256, 0, stream>>>(Vv, Vt);
  attn_kernel<<<dim3(64, 16), 256, 0, stream>>>(Qs, Ks, Vt, abias, attO);
  gemm_bt<1><<<dim3(64, 4), 256, 0, stream>>>(attO, wobf, b_out, nullptr, nullptr, nullptr, out);
}